// Round 4
// baseline (122.620 us; speedup 1.0000x reference)
//
#include <hip/hip_runtime.h>
#include <hip/hip_bf16.h>
#include <math.h>

#define NN 4096
#define DD 128

typedef __attribute__((ext_vector_type(8))) short bf16x8;
typedef __attribute__((ext_vector_type(4))) float f32x4;

// Pre-convert F (f32 [d][i], column-read coalesced) -> bf16 transposed [i][d].
__global__ __launch_bounds__(256)
void convert_kernel(const float* __restrict__ FP, const float* __restrict__ FM,
                    __hip_bfloat16* __restrict__ FPb, __hip_bfloat16* __restrict__ FMb)
{
    const float* src = blockIdx.y ? FM : FP;
    __hip_bfloat16* dst = blockIdx.y ? FMb : FPb;
    const int t  = threadIdx.x;
    const int il = t & 127;
    const int dh = t >> 7;
    const int i  = blockIdx.x * 128 + il;
    #pragma unroll
    for (int it = 0; it < 8; ++it) {
        const int d0 = dh * 64 + it * 8;
        union { __hip_bfloat162 h[4]; bf16x8 v; } p;
        #pragma unroll
        for (int j = 0; j < 4; ++j) {
            const float a = src[(long)(d0 + 2*j)     * NN + i];
            const float b = src[(long)(d0 + 2*j + 1) * NN + i];
            p.h[j] = __float22bfloat162_rn(make_float2(a, b));
        }
        *(bf16x8*)&dst[(long)i * DD + d0] = p.v;
    }
}

// Persistent gemm-loss: 256 blocks x 4 waves; each wave owns 12 consecutive
// 64x64 S tiles (64 i-tiles x 64 j-tiles x 3 gemms = 12288 tiles / 1024 waves).
// S lives in registers (depth-1 double buffer svA/svB); frags from L2-resident
// bf16 F. Issue order per iter pins counted vmcnt waits:
//   frags(t)[32] | S(t+1) half1[32] | MFMA (waits vmcnt(32) -> frags+S(t) done,
//   S(t+1)h1 still in flight) | epilogue (no wait) | S(t+1) half2[32]
__global__ __launch_bounds__(256, 1)
void gemm_loss_persist(const float* __restrict__ SU, const float* __restrict__ SP,
                       const float* __restrict__ SM,
                       const __hip_bfloat16* __restrict__ FPb_,
                       const __hip_bfloat16* __restrict__ FMb_,
                       double* __restrict__ accum)
{
    const short* FPb = (const short*)FPb_;
    const short* FMb = (const short*)FMb_;
    const int t0   = threadIdx.x;
    const int lane = t0 & 63;
    const int wid  = t0 >> 6;
    const int l15  = lane & 15, l4 = lane >> 4;
    const int w    = blockIdx.x * 4 + wid;   // 0..1023
    const int base = w * 12;
    const int last = base + 11;

    float svA[64], svB[64];
    float lsum = 0.f;

#define LOAD_S_HALF(tt, dst, mlo, mhi)                                          \
    {                                                                           \
        const int zz  = (tt) >> 12;                                             \
        const int ii0 = (((tt) >> 6) & 63) << 6;                                \
        const int jj0 = ((tt) & 63) << 6;                                       \
        const float* Sz_ = (zz == 0) ? SU : (zz == 1) ? SP : SM;                \
        _Pragma("unroll")                                                       \
        for (int m = (mlo); m < (mhi); ++m)                                     \
            _Pragma("unroll")                                                   \
            for (int n = 0; n < 4; ++n)                                         \
                _Pragma("unroll")                                               \
                for (int r = 0; r < 4; ++r)                                     \
                    dst[m*16 + n*4 + r] =                                       \
                        Sz_[(long)(ii0 + m*16 + l4*4 + r) * NN + jj0 + n*16 + l15]; \
    }

#define ITER(tt, cur, nxt)                                                      \
    {                                                                           \
        const int tc = (tt);                                                    \
        const int z  = tc >> 12;                                                \
        const int i0 = ((tc >> 6) & 63) << 6;                                   \
        const int j0 = (tc & 63) << 6;                                          \
        const short* Fa = (z == 2) ? FMb : FPb;                                 \
        const short* Fb = (z == 0) ? FMb : (z == 1) ? FPb : FMb;                \
        const float eps = (z == 0) ? 0.0f : 1e-8f;                              \
        bf16x8 af[4][4], bg[4][4];                                              \
        _Pragma("unroll")                                                       \
        for (int kb = 0; kb < 4; ++kb)                                          \
            _Pragma("unroll")                                                   \
            for (int m = 0; m < 4; ++m) {                                       \
                af[kb][m] = *(const bf16x8*)&Fa[(long)(i0 + m*16 + l15) * DD + kb*32 + l4*8]; \
                bg[kb][m] = *(const bf16x8*)&Fb[(long)(j0 + m*16 + l15) * DD + kb*32 + l4*8]; \
            }                                                                   \
        __builtin_amdgcn_sched_barrier(0);                                      \
        const int tn = (tc < last) ? tc + 1 : last;                             \
        LOAD_S_HALF(tn, nxt, 0, 2);                                             \
        __builtin_amdgcn_sched_barrier(0);                                      \
        f32x4 acc[4][4] = {};                                                   \
        _Pragma("unroll")                                                       \
        for (int kb = 0; kb < 4; ++kb)                                          \
            _Pragma("unroll")                                                   \
            for (int m = 0; m < 4; ++m)                                         \
                _Pragma("unroll")                                               \
                for (int n = 0; n < 4; ++n)                                     \
                    acc[m][n] = __builtin_amdgcn_mfma_f32_16x16x32_bf16(af[kb][m], bg[kb][n], acc[m][n], 0, 0, 0); \
        __builtin_amdgcn_sched_barrier(0);                                      \
        _Pragma("unroll")                                                       \
        for (int m = 0; m < 4; ++m)                                             \
            _Pragma("unroll")                                                   \
            for (int n = 0; n < 4; ++n)                                         \
                _Pragma("unroll")                                               \
                for (int r = 0; r < 4; ++r) {                                   \
                    const float o = 0.5f * acc[m][n][r];                        \
                    lsum += fmaf(-cur[m*16 + n*4 + r], o, __logf(1.0f + o + eps)); \
                }                                                               \
        __builtin_amdgcn_sched_barrier(0);                                      \
        LOAD_S_HALF(tn, nxt, 2, 4);                                             \
        __builtin_amdgcn_sched_barrier(0);                                      \
    }

    // prologue: full S(0) into svA
    LOAD_S_HALF(base, svA, 0, 4);

    #pragma unroll 1
    for (int k = 0; k < 12; k += 2) {
        ITER(base + k,     svA, svB);
        ITER(base + k + 1, svB, svA);
    }

    float v = lsum;
    #pragma unroll
    for (int off = 32; off; off >>= 1) v += __shfl_down(v, off);
    if (lane == 0) atomicAdd(accum, (double)v);
#undef ITER
#undef LOAD_S_HALF
}

// ---------------- fallback path (round-2 kernel, used if ws too small) ------
__global__ __launch_bounds__(256, 2)
void gemm_loss_mfma(const float* __restrict__ S, const float* __restrict__ F1,
                    const float* __restrict__ F2, float eps, double* __restrict__ accum)
{
    __shared__ char lds[2][128 * 256];
    __shared__ float red[4];
    const int t  = threadIdx.x;
    const int i0 = blockIdx.y * 128;
    const int j0 = blockIdx.x * 128;
    {
        const int il   = t & 127;
        const int half = t >> 7;
        const float* c1 = F1 + i0 + il;
        const float* c2 = F2 + j0 + il;
        char* r1 = lds[0] + il * 256;
        char* r2 = lds[1] + il * 256;
        #pragma unroll
        for (int it = 0; it < 8; ++it) {
            const int q  = half * 8 + it;
            const int d0 = q * 8;
            float a[8], b[8];
            #pragma unroll
            for (int j = 0; j < 8; ++j) {
                a[j] = c1[(long)(d0 + j) * NN];
                b[j] = c2[(long)(d0 + j) * NN];
            }
            union { __hip_bfloat162 h[4]; bf16x8 v; } pa, pb;
            #pragma unroll
            for (int j = 0; j < 4; ++j) {
                pa.h[j] = __float22bfloat162_rn(make_float2(a[2*j], a[2*j+1]));
                pb.h[j] = __float22bfloat162_rn(make_float2(b[2*j], b[2*j+1]));
            }
            const int off = (q ^ (il & 15)) << 4;
            *(bf16x8*)(r1 + off) = pa.v;
            *(bf16x8*)(r2 + off) = pb.v;
        }
    }
    __syncthreads();
    const int lane = t & 63;
    const int wid  = t >> 6;
    const int wr   = wid >> 1, wc = wid & 1;
    const int l15  = lane & 15, l4 = lane >> 4;
    float sreg[4][4][4];
    #pragma unroll
    for (int am = 0; am < 4; ++am)
        #pragma unroll
        for (int r = 0; r < 4; ++r) {
            const long gi   = (long)(i0 + wr * 64 + am * 16 + l4 * 4 + r);
            const long basep = gi * NN + j0 + wc * 64 + l15;
            #pragma unroll
            for (int bn = 0; bn < 4; ++bn)
                sreg[am][bn][r] = S[basep + bn * 16];
        }
    f32x4 acc[4][4] = {};
    #pragma unroll
    for (int kb = 0; kb < 4; ++kb) {
        bf16x8 af[4], bgr[4];
        #pragma unroll
        for (int m = 0; m < 4; ++m) {
            const int ia = wr * 64 + m * 16 + l15;
            af[m] = *(const bf16x8*)(lds[0] + ia * 256 + (((kb * 4 + l4) ^ l15) << 4));
            const int jb = wc * 64 + m * 16 + l15;
            bgr[m] = *(const bf16x8*)(lds[1] + jb * 256 + (((kb * 4 + l4) ^ l15) << 4));
        }
        #pragma unroll
        for (int m = 0; m < 4; ++m)
            #pragma unroll
            for (int n = 0; n < 4; ++n)
                acc[m][n] = __builtin_amdgcn_mfma_f32_16x16x32_bf16(af[m], bgr[n], acc[m][n], 0, 0, 0);
    }
    float lsum = 0.f;
    #pragma unroll
    for (int m = 0; m < 4; ++m)
        #pragma unroll
        for (int n = 0; n < 4; ++n)
            #pragma unroll
            for (int r = 0; r < 4; ++r) {
                const float o = 0.5f * acc[m][n][r];
                lsum += fmaf(-sreg[m][n][r], o, __logf(1.0f + o + eps));
            }
    float v = lsum;
    #pragma unroll
    for (int off = 32; off; off >>= 1) v += __shfl_down(v, off);
    if ((t & 63) == 0) red[t >> 6] = v;
    __syncthreads();
    if (t == 0) {
        const float tot = red[0] + red[1] + red[2] + red[3];
        atomicAdd(accum, (double)tot);
    }
}

// ---------------- small kernels ----------------
__global__ __launch_bounds__(256)
void bqc_kernel(const float* __restrict__ FP, const float* __restrict__ FM,
                const float* __restrict__ B, double* __restrict__ ws)
{
    __shared__ float red1[4], red2[4];
    const int n4 = DD * NN / 4;
    float s1 = 0.f, s2 = 0.f;
    for (int i = blockIdx.x * blockDim.x + threadIdx.x; i < n4;
         i += gridDim.x * blockDim.x) {
        const float4 p = ((const float4*)FP)[i];
        const float4 m = ((const float4*)FM)[i];
        const float4 b = ((const float4*)B)[i];
        float d;
        d = p.x - b.x; s1 += d * d;  d = p.y - b.y; s1 += d * d;
        d = p.z - b.z; s1 += d * d;  d = p.w - b.w; s1 += d * d;
        d = m.x - b.x; s2 += d * d;  d = m.y - b.y; s2 += d * d;
        d = m.z - b.z; s2 += d * d;  d = m.w - b.w; s2 += d * d;
    }
    const int t = threadIdx.x;
    #pragma unroll
    for (int off = 32; off; off >>= 1) {
        s1 += __shfl_down(s1, off);
        s2 += __shfl_down(s2, off);
    }
    if ((t & 63) == 0) { red1[t >> 6] = s1; red2[t >> 6] = s2; }
    __syncthreads();
    if (t == 0) {
        atomicAdd(&ws[1], (double)(red1[0] + red1[1] + red1[2] + red1[3]));
        atomicAdd(&ws[2], (double)(red2[0] + red2[1] + red2[2] + red2[3]));
    }
}

__global__ __launch_bounds__(256)
void fdc_kernel(const float* __restrict__ FP, const float* __restrict__ FM,
                double* __restrict__ ws)
{
    __shared__ float red[4];
    const float* F = (blockIdx.x >= DD) ? FM : FP;
    const int row = blockIdx.x & (DD - 1);
    float s = 0.f;
    const float4* rowp = (const float4*)&F[(long)row * NN];
    for (int i = threadIdx.x; i < NN / 4; i += blockDim.x) {
        const float4 v = rowp[i];
        s += v.x + v.y + v.z + v.w;
    }
    const int t = threadIdx.x;
    #pragma unroll
    for (int off = 32; off; off >>= 1) s += __shfl_down(s, off);
    if ((t & 63) == 0) red[t >> 6] = s;
    __syncthreads();
    if (t == 0) {
        const double rs = (double)(red[0] + red[1] + red[2] + red[3]);
        atomicAdd(&ws[3], rs * rs);
    }
}

__global__ void finalize_kernel(const double* __restrict__ ws, float* __restrict__ out)
{
    if (threadIdx.x == 0 && blockIdx.x == 0)
        out[0] = (float)(ws[0] + ws[3] + sqrt(ws[1]) + sqrt(ws[2]));
}

extern "C" void kernel_launch(void* const* d_in, const int* in_sizes, int n_in,
                              void* d_out, int out_size, void* d_ws, size_t ws_size,
                              hipStream_t stream)
{
    const float* SU = (const float*)d_in[0];
    const float* SP = (const float*)d_in[1];
    const float* SM = (const float*)d_in[2];
    const float* FP = (const float*)d_in[3];
    const float* FM = (const float*)d_in[4];
    const float* B  = (const float*)d_in[5];
    float*  out = (float*)d_out;
    double* ws  = (double*)d_ws;

    hipMemsetAsync(d_ws, 0, 4 * sizeof(double), stream);

    const size_t fb_bytes = (size_t)NN * DD * sizeof(__hip_bfloat16);   // 1 MB
    const size_t need     = 4096 + 2 * fb_bytes;

    if (ws_size >= need) {
        __hip_bfloat16* FPb = (__hip_bfloat16*)((char*)d_ws + 4096);
        __hip_bfloat16* FMb = (__hip_bfloat16*)((char*)d_ws + 4096 + fb_bytes);
        convert_kernel<<<dim3(NN / 128, 2), 256, 0, stream>>>(FP, FM, FPb, FMb);
        gemm_loss_persist<<<256, 256, 0, stream>>>(SU, SP, SM, FPb, FMb, ws);
    } else {
        dim3 grid(NN / 128, NN / 128);
        gemm_loss_mfma<<<grid, 256, 0, stream>>>(SU, FP, FM, 0.0f, ws);
        gemm_loss_mfma<<<grid, 256, 0, stream>>>(SP, FP, FP, 1e-8f, ws);
        gemm_loss_mfma<<<grid, 256, 0, stream>>>(SM, FM, FM, 1e-8f, ws);
    }
    bqc_kernel<<<512, 256, 0, stream>>>(FP, FM, B, ws);
    fdc_kernel<<<256, 256, 0, stream>>>(FP, FM, ws);
    finalize_kernel<<<1, 64, 0, stream>>>(ws, out);
}